// Round 2
// baseline (1824.028 us; speedup 1.0000x reference)
//
#include <hip/hip_runtime.h>

#define NFEAT  64
#define NCLS   100
#define ACC    (NCLS * NFEAT)   // 6400
#define UNROLL 8
#define BLK    1024             // 16 waves; LDS 51.7KB -> 2 blocks/CU = 32 waves/CU
#define GRID   512              // 2 blocks/CU on 256 CUs

// ws layout (words): [0,6400) s, [6400,12800) ss, [12800,12900) counts(uint)
__global__ void zero_ws_kernel(float* ws) {
    int i = blockIdx.x * blockDim.x + threadIdx.x;
    if (i < 2 * ACC + NCLS) ws[i] = 0.0f;
}

__global__ __launch_bounds__(256, 4)
void hist_kernel(const int* __restrict__ t, unsigned int* __restrict__ gcnt, int n) {
    __shared__ unsigned int h[NCLS];
    if (threadIdx.x < NCLS) h[threadIdx.x] = 0u;
    __syncthreads();
    const int stride = gridDim.x * blockDim.x;
    for (int i = blockIdx.x * blockDim.x + threadIdx.x; i < n; i += stride)
        atomicAdd(&h[t[i]], 1u);
    __syncthreads();
    if (threadIdx.x < NCLS) {
        unsigned int v = h[threadIdx.x];
        if (v) atomicAdd(&gcnt[threadIdx.x], v);
    }
}

__global__ __launch_bounds__(BLK, 8)   // 8 waves/EU -> VGPR cap 64 -> 32 waves/CU
void accum_kernel(const float* __restrict__ x, const int* __restrict__ t,
                  float* __restrict__ gs, float* __restrict__ gss, int nrows) {
    __shared__ float ls [ACC];
    __shared__ float lss[ACC];

    const int tid = threadIdx.x;
    for (int i = tid; i < ACC; i += BLK) { ls[i] = 0.0f; lss[i] = 0.0f; }
    __syncthreads();

    const int lane   = tid & 63;
    const int wave   = tid >> 6;
    const int nwaves = GRID * (BLK / 64);              // 8192
    const int gw     = blockIdx.x * (BLK / 64) + wave;
    const long long step = (long long)nwaves * UNROLL; // 65536 rows/sweep

    long long row0 = (long long)gw * UNROLL;
    // full tiles: 8 independent t loads + 8 independent x loads (MLP=8), then LDS atomics
    for (; row0 + UNROLL <= nrows; row0 += step) {
        const int*   tp = t + row0;
        const float* xp = x + row0 * NFEAT + lane;
        int   c[UNROLL];
        float v[UNROLL];
#pragma unroll
        for (int u = 0; u < UNROLL; u++) c[u] = __builtin_amdgcn_readfirstlane(tp[u]);
#pragma unroll
        for (int u = 0; u < UNROLL; u++) v[u] = xp[u * NFEAT];
#pragma unroll
        for (int u = 0; u < UNROLL; u++) {
            const int base = c[u] * NFEAT + lane;      // 2-way bank alias: free
            unsafeAtomicAdd(&ls [base], v[u]);
            unsafeAtomicAdd(&lss[base], v[u] * v[u]);
        }
    }
    // tail
    for (; row0 < nrows; row0++) {
        const int   c = __builtin_amdgcn_readfirstlane(t[row0]);
        const float v = x[row0 * NFEAT + lane];
        const int base = c * NFEAT + lane;
        unsafeAtomicAdd(&ls [base], v);
        unsafeAtomicAdd(&lss[base], v * v);
    }
    __syncthreads();

    for (int i = tid; i < ACC; i += BLK) {
        unsafeAtomicAdd(&gs [i], ls [i]);
        unsafeAtomicAdd(&gss[i], lss[i]);
    }
}

__global__ void finalize_kernel(const float* __restrict__ gs,
                                const float* __restrict__ gss,
                                const unsigned int* __restrict__ gcnt,
                                float* __restrict__ out) {
    __shared__ double red[256];
    double acc = 0.0;
    for (int i = threadIdx.x; i < ACC; i += 256) {
        const int c = i >> 6;
        const double n  = (double)gcnt[c];
        const double s  = (double)gs[i];
        const double ss = (double)gss[i];
        acc += (ss - s * s / n) / (n - 1.0);
    }
    red[threadIdx.x] = acc;
    __syncthreads();
    for (int off = 128; off > 0; off >>= 1) {
        if (threadIdx.x < off) red[threadIdx.x] += red[threadIdx.x + off];
        __syncthreads();
    }
    if (threadIdx.x == 0) out[0] = (float)(red[0] / (double)NCLS);
}

extern "C" void kernel_launch(void* const* d_in, const int* in_sizes, int n_in,
                              void* d_out, int out_size, void* d_ws, size_t ws_size,
                              hipStream_t stream) {
    const float* x = (const float*)d_in[0];
    const int*   t = (const int*)d_in[1];
    const int nrows = in_sizes[1];           // 2,000,000

    float* gs = (float*)d_ws;
    float* gss = gs + ACC;
    unsigned int* gcnt = (unsigned int*)(gss + ACC);

    const int zwords = 2 * ACC + NCLS;       // 12,900
    zero_ws_kernel<<<(zwords + 255) / 256, 256, 0, stream>>>((float*)d_ws);
    hist_kernel<<<256, 256, 0, stream>>>(t, gcnt, nrows);
    accum_kernel<<<GRID, BLK, 0, stream>>>(x, t, gs, gss, nrows);
    finalize_kernel<<<1, 256, 0, stream>>>(gs, gss, gcnt, (float*)d_out);
}

// Round 3
// 717.680 us; speedup vs baseline: 2.5416x; 2.5416x over previous
//
#include <hip/hip_runtime.h>

#define NFEAT 64
#define NCLS  100
#define ACC   (NCLS * NFEAT)   // 6400
#define NB    512              // hist/scatter blocks
#define ABLK  256
#define AGRID 2048             // accum blocks: 8/CU -> 32 waves/CU

// ws layout in 32-bit words:
#define OFF_GS    0                      // 6400 f32
#define OFF_GSS   6400                   // 6400 f32
#define OFF_GCNT  12800                  // 100 u32
#define OFF_CB    12928                  // 101 u32 (classBase, exclusive prefix)
#define OFF_BCNT  13056                  // NB*NCLS u32
#define OFF_ORDER (13056 + NB * NCLS)    // nrows i32

__global__ void zero_ws_kernel(float* ws) {
    int i = blockIdx.x * blockDim.x + threadIdx.x;
    if (i < 2 * ACC + NCLS) ws[i] = 0.0f;   // gs, gss, gcnt
}

__global__ __launch_bounds__(256, 4)
void hist_kernel(const int* __restrict__ t, unsigned* __restrict__ bcnt,
                 unsigned* __restrict__ gcnt, int n, int chunk) {
    __shared__ unsigned h[NCLS];
    for (int i = threadIdx.x; i < NCLS; i += 256) h[i] = 0u;
    __syncthreads();
    const int b = blockIdx.x, s = b * chunk, e = min(n, s + chunk);
    for (int i = s + threadIdx.x; i < e; i += 256) atomicAdd(&h[t[i]], 1u);
    __syncthreads();
    for (int c = threadIdx.x; c < NCLS; c += 256) {
        bcnt[b * NCLS + c] = h[c];
        atomicAdd(&gcnt[c], h[c]);
    }
}

__global__ void prefix_kernel(const unsigned* __restrict__ gcnt,
                              unsigned* __restrict__ cb,
                              unsigned* __restrict__ bcnt, int n) {
    if (threadIdx.x == 0) {
        unsigned r = 0;
        for (int c = 0; c < NCLS; c++) { cb[c] = r; r += gcnt[c]; }
        cb[NCLS] = r;   // == n
    }
    __syncthreads();
    const int c = threadIdx.x;
    if (c < NCLS) {
        unsigned run = cb[c];
        for (int b = 0; b < NB; b++) {
            unsigned v = bcnt[b * NCLS + c];
            bcnt[b * NCLS + c] = run;
            run += v;
        }
    }
}

__global__ __launch_bounds__(256, 4)
void scatter_kernel(const int* __restrict__ t, const unsigned* __restrict__ bcnt,
                    int* __restrict__ order, int n, int chunk) {
    __shared__ unsigned cur[NCLS];
    const int b = blockIdx.x;
    for (int c = threadIdx.x; c < NCLS; c += 256) cur[c] = bcnt[b * NCLS + c];
    __syncthreads();
    const int s = b * chunk, e = min(n, s + chunk);
    for (int i = s + threadIdx.x; i < e; i += 256) {
        const int c = t[i];
        const unsigned p = atomicAdd(&cur[c], 1u);
        order[p] = i;
    }
}

__global__ __launch_bounds__(ABLK, 8)   // cap VGPR<=64 -> 32 waves/CU
void accum_sorted(const float* __restrict__ x, const int* __restrict__ order,
                  const unsigned* __restrict__ cb_g,
                  float* __restrict__ gs, float* __restrict__ gss,
                  int n, int ch) {
    __shared__ unsigned cb[NCLS + 1];
    for (int i = threadIdx.x; i < NCLS + 1; i += ABLK) cb[i] = cb_g[i];
    __syncthreads();

    const int lane = threadIdx.x & 63;
    const int gw = blockIdx.x * (ABLK / 64) + (threadIdx.x >> 6);
    long long i0 = (long long)gw * ch;
    long long i1 = min((long long)n, i0 + ch);
    if (i0 >= i1) return;

    // largest c with cb[c] <= i0
    int lo = 0, hi = NCLS - 1;
    while (lo < hi) {
        const int mid = (lo + hi + 1) >> 1;
        if ((long long)cb[mid] <= i0) lo = mid; else hi = mid - 1;
    }
    int c = lo;

    while (i0 < i1 && c < NCLS) {
        const long long segEnd = min(i1, (long long)cb[c + 1]);
        if (segEnd > i0) {
            float s = 0.0f, ss = 0.0f;
            long long i = i0;
            for (; i + 8 <= segEnd; i += 8) {
                const int* op = order + i;
                int r[8];
#pragma unroll
                for (int u = 0; u < 8; u++) r[u] = __builtin_amdgcn_readfirstlane(op[u]);
                float v[8];
#pragma unroll
                for (int u = 0; u < 8; u++) v[u] = x[(long long)r[u] * NFEAT + lane];
#pragma unroll
                for (int u = 0; u < 8; u++) { s += v[u]; ss += v[u] * v[u]; }
            }
            for (; i < segEnd; i++) {
                const int r = __builtin_amdgcn_readfirstlane(order[i]);
                const float v = x[(long long)r * NFEAT + lane];
                s += v; ss += v * v;
            }
            const int base = c * NFEAT + lane;
            unsafeAtomicAdd(&gs[base], s);
            unsafeAtomicAdd(&gss[base], ss);
        }
        i0 = segEnd; c++;
    }
}

__global__ void finalize_kernel(const float* __restrict__ gs,
                                const float* __restrict__ gss,
                                const unsigned int* __restrict__ gcnt,
                                float* __restrict__ out) {
    __shared__ double red[256];
    double acc = 0.0;
    for (int i = threadIdx.x; i < ACC; i += 256) {
        const int c = i >> 6;
        const double n  = (double)gcnt[c];
        const double s  = (double)gs[i];
        const double ss = (double)gss[i];
        acc += (ss - s * s / n) / (n - 1.0);
    }
    red[threadIdx.x] = acc;
    __syncthreads();
    for (int off = 128; off > 0; off >>= 1) {
        if (threadIdx.x < off) red[threadIdx.x] += red[threadIdx.x + off];
        __syncthreads();
    }
    if (threadIdx.x == 0) out[0] = (float)(red[0] / (double)NCLS);
}

// ---------- fallback (round-2 path) if ws too small for order[] ----------
__global__ __launch_bounds__(1024, 8)
void accum_fallback(const float* __restrict__ x, const int* __restrict__ t,
                    float* __restrict__ gs, float* __restrict__ gss, int nrows) {
    __shared__ float ls[ACC];
    __shared__ float lss[ACC];
    const int tid = threadIdx.x;
    for (int i = tid; i < ACC; i += 1024) { ls[i] = 0.0f; lss[i] = 0.0f; }
    __syncthreads();
    const int lane = tid & 63, wave = tid >> 6;
    const long long step = (long long)512 * 16 * 8;
    long long row0 = ((long long)blockIdx.x * 16 + wave) * 8;
    for (; row0 + 8 <= nrows; row0 += step) {
        const int* tp = t + row0;
        const float* xp = x + row0 * NFEAT + lane;
        int c[8]; float v[8];
#pragma unroll
        for (int u = 0; u < 8; u++) c[u] = __builtin_amdgcn_readfirstlane(tp[u]);
#pragma unroll
        for (int u = 0; u < 8; u++) v[u] = xp[u * NFEAT];
#pragma unroll
        for (int u = 0; u < 8; u++) {
            const int base = c[u] * NFEAT + lane;
            unsafeAtomicAdd(&ls[base], v[u]);
            unsafeAtomicAdd(&lss[base], v[u] * v[u]);
        }
    }
    for (; row0 < nrows; row0++) {
        const int c = __builtin_amdgcn_readfirstlane(t[row0]);
        const float v = x[row0 * NFEAT + lane];
        unsafeAtomicAdd(&ls[c * NFEAT + lane], v);
        unsafeAtomicAdd(&lss[c * NFEAT + lane], v * v);
    }
    __syncthreads();
    for (int i = tid; i < ACC; i += 1024) {
        unsafeAtomicAdd(&gs[i], ls[i]);
        unsafeAtomicAdd(&gss[i], lss[i]);
    }
}

extern "C" void kernel_launch(void* const* d_in, const int* in_sizes, int n_in,
                              void* d_out, int out_size, void* d_ws, size_t ws_size,
                              hipStream_t stream) {
    const float* x = (const float*)d_in[0];
    const int*   t = (const int*)d_in[1];
    const int n = in_sizes[1];               // 2,000,000

    float*    wsf  = (float*)d_ws;
    unsigned* wsu  = (unsigned*)d_ws;
    float*    gs   = wsf + OFF_GS;
    float*    gss  = wsf + OFF_GSS;
    unsigned* gcnt = wsu + OFF_GCNT;
    unsigned* cb   = wsu + OFF_CB;
    unsigned* bcnt = wsu + OFF_BCNT;
    int*      order = (int*)(wsu + OFF_ORDER);

    const size_t needed = (size_t)(OFF_ORDER + n) * 4;
    const int zwords = 2 * ACC + NCLS;
    zero_ws_kernel<<<(zwords + 255) / 256, 256, 0, stream>>>((float*)d_ws);

    if (ws_size >= needed) {
        const int chunk = (n + NB - 1) / NB;
        hist_kernel<<<NB, 256, 0, stream>>>(t, bcnt, gcnt, n, chunk);
        prefix_kernel<<<1, 128, 0, stream>>>(gcnt, cb, bcnt, n);
        scatter_kernel<<<NB, 256, 0, stream>>>(t, bcnt, order, n, chunk);
        const int nw = AGRID * (ABLK / 64);
        const int ch = (n + nw - 1) / nw;
        accum_sorted<<<AGRID, ABLK, 0, stream>>>(x, order, cb, gs, gss, n, ch);
    } else {
        // hist for counts, fallback accumulation
        const int chunk = (n + NB - 1) / NB;
        hist_kernel<<<NB, 256, 0, stream>>>(t, bcnt, gcnt, n, chunk);
        accum_fallback<<<512, 1024, 0, stream>>>(x, t, gs, gss, n);
    }
    finalize_kernel<<<1, 256, 0, stream>>>(gs, gss, gcnt, (float*)d_out);
}